// Round 4
// baseline (17485.767 us; speedup 1.0000x reference)
//
#include <hip/hip_runtime.h>
#include <math.h>

#define V 13000
#define D 300
#define M 500
#define B 64
#define NW 5
#define T 128
#define NSUP (B*NW)       // 320
#define NSEQ (NSUP + B)   // 384
#define CT 64             // chains per tile (= lanes per wave)
#define NCT 6             // 384/64
#define MB 12             // m per compute block
#define NMB 42            // ceil(500/12) -> covers m 0..503 with clamp
#define NSLICE (2*NMB)    // 84 weight panels (dir, mb)
#define SPX 11            // ceil(84/8) slices per XCD
#define NKC 8             // K chunks of 100 (3 W-chunks + 5 U-chunks)
#define NCOMP (8*SPX*NCT) // 528 compute blocks (some idle)
#define NGATH (2*NSEQ)    // 768 gather blocks

__device__ __forceinline__ float sigmoidf_(float x){ return 1.0f/(1.0f+expf(-x)); }

// actT element (dir, k, rank):  actT[ ((dir*8 + k/100)*NSEQ + rank)*100 + k%100 ]
// k in [0,300) = x part (emb row of this step's token); k in [300,800) = c state.

__global__ void init_kernel(const float* __restrict__ c0L, const float* __restrict__ c0R,
                            float* __restrict__ actT0, float* __restrict__ c_final)
{
    int idx = blockIdx.x*256 + threadIdx.x;      // 2*384*500
    if (idx >= 2*NSEQ*M) return;
    int dir = idx / (NSEQ*M);
    int rem = idx % (NSEQ*M);
    int a = rem / NSEQ;                          // m 0..499
    int r = rem % NSEQ;                          // rank (also reused as chain below)
    float v = dir ? c0R[a] : c0L[a];
    c_final[((size_t)dir*NSEQ + r)*M + a] = v;
    int k = 300 + a;
    actT0[(((size_t)dir*NKC + (k/100))*NSEQ + r)*100 + (k%100)] = v;
}

__global__ void sort_kernel(const int* __restrict__ blank_sup, const int* __restrict__ blank_tgt,
                            int* __restrict__ perm, int* __restrict__ lenR, int* __restrict__ tmax)
{
    __shared__ int L0[NSEQ], L1[NSEQ];
    int tid = threadIdx.x;                       // 384 threads
    int blank = (tid < NSUP) ? blank_sup[tid] : blank_tgt[tid - NSUP];
    int l0 = blank, l1 = (T-1) - blank;
    L0[tid] = l0; L1[tid] = l1;
    __syncthreads();
    int r0 = 0, r1 = 0;
    for (int j = 0; j < NSEQ; ++j) {
        int c = L0[j]; r0 += (c > l0) || (c == l0 && j < tid);
        int d = L1[j]; r1 += (d > l1) || (d == l1 && j < tid);
    }
    perm[r0] = tid;        lenR[r0] = l0;
    perm[NSEQ + r1] = tid; lenR[NSEQ + r1] = l1;
    __syncthreads();
    if (tid < 2*NCT) {
        int dir = tid / NCT, t = tid % NCT;
        tmax[tid] = lenR[dir*NSEQ + t*CT];       // descending -> first rank in tile is max
    }
}

// -------- per-step fused kernel: 528 compute blocks (8 waves, K-split) + 768 gather blocks ----
__global__ __launch_bounds__(512)
void step_fused(int s,
                const float* __restrict__ actT_cur, float* __restrict__ actT_next,
                float* __restrict__ c_final,
                const float* __restrict__ WL, const float* __restrict__ UL, const float* __restrict__ bL,
                const float* __restrict__ WR, const float* __restrict__ UR, const float* __restrict__ bR,
                const int* __restrict__ perm, const int* __restrict__ lenR, const int* __restrict__ tmax,
                const int* __restrict__ sup_tok, const int* __restrict__ tgt_tok,
                const float* __restrict__ emb)
{
    __shared__ float red[4][9][64];              // K-split partial sums (9.2 KB)
    const int bid = blockIdx.x;
    if (bid < NCOMP) {
        if (s < 0) return;
        // XCD co-location: the 6 ct-blocks of a slice share bid%8 and are dispatch-adjacent
        const int x  = bid & 7;
        const int jj = bid >> 3;                 // 0..65
        const int ct = jj % NCT;
        const int sl = jj / NCT;                 // 0..10
        const int slice = sl*8 + x;              // 0..87
        if (slice >= NSLICE) return;
        const int dir = slice / NMB;
        const int mb  = slice % NMB;
        if (s >= tmax[dir*NCT + ct]) return;     // whole chain-tile finished

        const int wave  = threadIdx.x >> 6;      // 0..7
        const int lane  = threadIdx.x & 63;
        const int mgrp  = wave & 3;              // which 3-m group
        const int khalf = wave >> 2;             // 0: K 0..400, 1: K 400..800
        const int rank  = ct*CT + lane;
        const int len   = lenR[dir*NSEQ + rank];
        const int chain = perm[dir*NSEQ + rank];

        const float* Wd = dir ? WR : WL;
        const float* Ud = dir ? UR : UL;
        const float* bias = dir ? bR : bL;

        int mmu[3]; bool val[3];
        #pragma unroll
        for (int j = 0; j < 3; ++j) {
            int m = mb*MB + mgrp*3 + j;
            val[j] = (m < M);
            mmu[j] = __builtin_amdgcn_readfirstlane(m < M ? m : (M-1));
        }

        float acc[3][3];
        #pragma unroll
        for (int j = 0; j < 3; ++j)
            #pragma unroll
            for (int g = 0; g < 3; ++g)
                acc[j][g] = khalf ? 0.f : bias[g*M + mmu[j]];

        for (int kc = khalf*4; kc < khalf*4 + 4; ++kc) {
            const float4* ap = (const float4*)(actT_cur + (((size_t)dir*NKC + kc)*NSEQ + rank)*100);
            float4 a4[25];
            #pragma unroll
            for (int q = 0; q < 25; ++q) a4[q] = ap[q];

            const float* wb; size_t rs; int ko;
            if (kc < 3) { wb = Wd; rs = D; ko = kc*100; }
            else        { wb = Ud; rs = M; ko = kc*100 - 300; }

            #pragma unroll
            for (int j = 0; j < 3; ++j) {
                if (!val[j]) continue;           // wave-uniform
                #pragma unroll
                for (int g = 0; g < 3; ++g) {
                    const float4* wp = (const float4*)(wb + (size_t)(g*M + mmu[j])*rs + ko);
                    float s0 = 0.f, s1 = 0.f, s2 = 0.f, s3 = 0.f;
                    #pragma unroll
                    for (int q = 0; q < 25; ++q) {
                        float4 w = wp[q];
                        s0 += w.x * a4[q].x;
                        s1 += w.y * a4[q].y;
                        s2 += w.z * a4[q].z;
                        s3 += w.w * a4[q].w;
                    }
                    acc[j][g] += (s0 + s1) + (s2 + s3);
                }
            }
        }

        if (khalf) {
            #pragma unroll
            for (int j = 0; j < 3; ++j)
                #pragma unroll
                for (int g = 0; g < 3; ++g)
                    red[wave-4][j*3+g][lane] = acc[j][g];
        }
        __syncthreads();
        if (!khalf) {
            #pragma unroll
            for (int j = 0; j < 3; ++j) {
                if (!val[j]) continue;
                #pragma unroll
                for (int g = 0; g < 3; ++g) acc[j][g] += red[wave][j*3+g][lane];
                const int m = mb*MB + mgrp*3 + j;
                const int k = 300 + m;
                const size_t aidx = (((size_t)dir*NKC + (k/100))*NSEQ + rank)*100 + (k%100);
                float cold = actT_cur[aidx];
                float f  = sigmoidf_(acc[j][0]);
                float i2 = sigmoidf_(acc[j][1]);
                float cb = tanhf(acc[j][2]);
                float cn = (s < len) ? (f*cold + i2*cb) : cold;
                actT_next[aidx] = cn;
                if (s == len - 1) c_final[((size_t)dir*NSEQ + chain)*M + m] = cn;
            }
        }
    } else {
        // gather x-part for step s+1 into actT_next
        const int gb = bid - NCOMP;              // 0..767
        const int dir = gb / NSEQ;
        const int rank = gb % NSEQ;
        const int sn = s + 1;
        if (sn >= T-1) return;
        if (sn >= tmax[dir*NCT + rank/CT]) return;
        const int ch = perm[dir*NSEQ + rank];
        const int tpos = dir ? (T-1 - sn) : sn;
        const int tok = (ch < NSUP) ? sup_tok[ch*T + tpos] : tgt_tok[(ch - NSUP)*T + tpos];
        const float* src = emb + (size_t)tok*D;
        for (int k = threadIdx.x; k < D; k += 512) {
            actT_next[(((size_t)dir*NKC + (k/100))*NSEQ + rank)*100 + (k%100)] = src[k];
        }
    }
}

__global__ void env_kernel(const float* __restrict__ l_states, const float* __restrict__ r_states,
                           const float* __restrict__ Wo, const float* __restrict__ Uo,
                           const float* __restrict__ bo,
                           float* __restrict__ env)
{
    __shared__ __align__(16) float l[M];
    __shared__ __align__(16) float r[M];
    const int i = blockIdx.x;
    const int tid = threadIdx.x;
    for (int m=tid; m<M; m+=blockDim.x){ l[m]=l_states[i*M+m]; r[m]=r_states[i*M+m]; }
    __syncthreads();
    for (int d=tid; d<D; d+=blockDim.x) {
        const float4* wo = reinterpret_cast<const float4*>(Wo + (size_t)d*M);
        const float4* uo = reinterpret_cast<const float4*>(Uo + (size_t)d*M);
        const float4* lv = reinterpret_cast<const float4*>(l);
        const float4* rv = reinterpret_cast<const float4*>(r);
        float acc = bo[d];
        #pragma unroll 5
        for (int q=0; q<M/4; ++q) {
            float4 a=wo[q], bv=lv[q], u=uo[q], rr=rv[q];
            acc += a.x*bv.x + a.y*bv.y + a.z*bv.z + a.w*bv.w;
            acc += u.x*rr.x + u.y*rr.y + u.z*rr.z + u.w*rr.w;
        }
        env[i*D + d] = tanhf(acc);
    }
}

__global__ void episode_kernel(const float* __restrict__ env, const int* __restrict__ target_y,
                               float* __restrict__ flags, float* __restrict__ losses)
{
    const int b = blockIdx.x;
    const int lane = threadIdx.x;
    const float* tgt = env + (size_t)(NSUP + b)*D;

    float tn = 0.f;
    for (int d=lane; d<D; d+=64){ float v=tgt[d]; tn += v*v; }
    for (int off=32; off; off>>=1) tn += __shfl_down(tn, off);
    tn = __shfl(tn, 0);

    float z[NW];
    for (int n=0; n<NW; ++n){
        const float* sup = env + (size_t)(b*NW + n)*D;
        float dot=0.f, sn=0.f;
        for (int d=lane; d<D; d+=64){ float sv=sup[d], tv=tgt[d]; dot+=sv*tv; sn+=sv*sv; }
        for (int off=32; off; off>>=1){ dot += __shfl_down(dot,off); sn += __shfl_down(sn,off); }
        dot = __shfl(dot,0); sn = __shfl(sn,0);
        float denom = fmaxf(sqrtf(sn)*sqrtf(tn), 1e-8f);
        z[n] = dot/denom*10.0f;
    }

    if (lane==0){
        float mx=z[0];
        for(int n=1;n<NW;n++) mx=fmaxf(mx,z[n]);
        float se=0.f; float p[NW];
        for(int n=0;n<NW;n++){ p[n]=expf(z[n]-mx); se+=p[n]; }
        for(int n=0;n<NW;n++) p[n]/=se;
        int am=0; float bv=p[0];
        for(int n=1;n<NW;n++) if(p[n]>bv){bv=p[n];am=n;}
        int y = target_y[b];
        flags[b] = (am==y)?1.0f:0.0f;
        float mx2=p[0]; for(int n=1;n<NW;n++) mx2=fmaxf(mx2,p[n]);
        float se2=0.f; for(int n=0;n<NW;n++) se2+=expf(p[n]-mx2);
        losses[b] = -(p[y]-mx2-logf(se2));
    }
}

__global__ void finalize_kernel(const float* __restrict__ flags, const float* __restrict__ losses,
                                float* __restrict__ out)
{
    const int lane = threadIdx.x; // 64 threads
    float f = flags[lane], l = losses[lane];
    for (int off=32; off; off>>=1){ f += __shfl_down(f,off); l += __shfl_down(l,off); }
    if (lane==0){ out[0] = f/(float)B; out[1] = l/(float)B; }
}

extern "C" void kernel_launch(void* const* d_in, const int* in_sizes, int n_in,
                              void* d_out, int out_size, void* d_ws, size_t ws_size,
                              hipStream_t stream) {
    const int*   sup_tok   = (const int*)d_in[0];
    const int*   tgt_tok   = (const int*)d_in[1];
    const int*   blank_sup = (const int*)d_in[2];
    const int*   blank_tgt = (const int*)d_in[3];
    const int*   target_y  = (const int*)d_in[4];
    const float* emb = (const float*)d_in[5];
    const float* WL  = (const float*)d_in[6];
    const float* UL  = (const float*)d_in[7];
    const float* bL  = (const float*)d_in[8];
    const float* WR  = (const float*)d_in[9];
    const float* UR  = (const float*)d_in[10];
    const float* bR  = (const float*)d_in[11];
    const float* Wo  = (const float*)d_in[12];
    const float* Uo  = (const float*)d_in[13];
    const float* bo  = (const float*)d_in[14];
    const float* c0L = (const float*)d_in[15];
    const float* c0R = (const float*)d_in[16];

    const size_t ACTSZ = (size_t)2*NKC*NSEQ*100;   // 614400 floats per buffer
    float* ws_f = (float*)d_ws;
    float* actT0   = ws_f;
    float* actT1   = actT0 + ACTSZ;
    float* c_final = actT1 + ACTSZ;                // [2*384*500]
    float* env     = c_final + 2*NSEQ*M;           // [384*300]
    float* flags   = env + NSEQ*D;                 // [64]
    float* losses  = flags + B;                    // [64]
    int*   perm    = (int*)(losses + B);           // [2*384]
    int*   lenR    = perm + 2*NSEQ;                // [2*384]
    int*   tmax    = lenR + 2*NSEQ;                // [12]

    init_kernel<<<(2*NSEQ*M + 255)/256, 256, 0, stream>>>(c0L, c0R, actT0, c_final);
    sort_kernel<<<1, NSEQ, 0, stream>>>(blank_sup, blank_tgt, perm, lenR, tmax);

    // prologue: gather x for step 0 into actT0 (compute blocks no-op at s=-1)
    step_fused<<<NCOMP + NGATH, 512, 0, stream>>>(-1, actT1, actT0, c_final,
                                                  WL, UL, bL, WR, UR, bR,
                                                  perm, lenR, tmax, sup_tok, tgt_tok, emb);
    for (int s = 0; s < T-1; ++s) {
        float* cur  = (s & 1) ? actT1 : actT0;
        float* next = (s & 1) ? actT0 : actT1;
        step_fused<<<NCOMP + NGATH, 512, 0, stream>>>(s, cur, next, c_final,
                                                      WL, UL, bL, WR, UR, bR,
                                                      perm, lenR, tmax, sup_tok, tgt_tok, emb);
    }

    env_kernel<<<NSEQ, 256, 0, stream>>>(c_final, c_final + NSEQ*M, Wo, Uo, bo, env);
    episode_kernel<<<B, 64, 0, stream>>>(env, target_y, flags, losses);
    finalize_kernel<<<1, 64, 0, stream>>>(flags, losses, (float*)d_out);
}